// Round 9
// baseline (280.872 us; speedup 1.0000x reference)
//
#include <hip/hip_runtime.h>
#include <cstddef>
#include <math.h>

// 3-kernel pipeline, numerics FROZEN to the passing R4..R8 recipe
// (absmax 0.015625 vs threshold 0.02): numpy-f32 op ordering everywhere —
// ascending per-bucket sums, scale-first softmax with pairwise-16 sum and
// true division, (i,j,k)-lex einsum with materialized-w rounding, f64-exact
// exp. R9 change vs R8: OCCUPANCY ONLY.
//   R8's K1 was latency-bound: launch_bounds(256,2) -> 8 waves/CU, ~1KB of
//   loads in flight, 2.5 TB/s. K1 and K3 now declare (256,4) -> 16 waves/CU,
//   doubling memory-level parallelism. No arithmetic or layout changes.

__device__ __forceinline__ float exf(float t) {
  return (float)exp((double)t);  // correctly-rounded f32 exp
}

// softmax(x*100) with numpy rounding/order.
__device__ __forceinline__ void softmax16_np(const float* x, float* p) {
#pragma clang fp contract(off)
  float t[16];
#pragma unroll
  for (int j = 0; j < 16; ++j) t[j] = x[j] * 100.0f;  // scale FIRST (rounded)
  float m = t[0];
#pragma unroll
  for (int j = 1; j < 16; ++j) m = fmaxf(m, t[j]);
  float e[16];
#pragma unroll
  for (int j = 0; j < 16; ++j) e[j] = exf(t[j] - m);
  float r0 = e[0] + e[8], r1 = e[1] + e[9], r2 = e[2] + e[10], r3 = e[3] + e[11];
  float r4 = e[4] + e[12], r5 = e[5] + e[13], r6 = e[6] + e[14], r7 = e[7] + e[15];
  float s = ((r0 + r1) + (r2 + r3)) + ((r4 + r5) + (r6 + r7));
#pragma unroll
  for (int j = 0; j < 16; ++j) p[j] = e[j] / s;  // true division
}

// Serial soft nibble add: raw sums s[16] (pre-softmax) + carry probs (n0,n1).
__device__ __forceinline__ void nibble_add_raw(const float* px, const float* py,
                                               float c0, float c1,
                                               float* s, float& n0, float& n1) {
#pragma clang fp contract(off)
  float ca = 0.f, cb = 0.f;
#pragma unroll
  for (int l = 0; l < 16; ++l) s[l] = 0.f;
#pragma unroll
  for (int i = 0; i < 16; ++i) {
#pragma unroll
    for (int j = 0; j < 16; ++j) {
      float wij = px[i] * py[j];
      float w0 = wij * c0;
      float w1 = wij * c1;
      const int t0 = i + j, t1 = i + j + 1;
      s[t0 & 15] += w0;
      if (t0 < 16) ca += w0; else cb += w0;
      s[t1 & 15] += w1;
      if (t1 < 16) ca += w1; else cb += w1;
    }
  }
  float u0 = ca * 100.0f, u1 = cb * 100.0f;
  float m = fmaxf(u0, u1);
  float e0 = exf(u0 - m), e1 = exf(u1 - m);
  float ss = e0 + e1;
  n0 = e0 / ss;
  n1 = e1 / ss;
}

// ---------------- K1: buckets + input softmax -> ws1 ----------------
// ws1 row r = (ib*2+inp)*32 + nib*16 + j  (256 rows x nbatch, batch-major)
// grid (nbatch/256, 4, 2), block 256. One thread = one 256-float row,
// streamed as 8 iterations x 128B with a register double-buffer.
extern "C" __global__ void __launch_bounds__(256, 4)
k1_prep(const float* __restrict__ A, const float* __restrict__ Bm,
        float* __restrict__ ws1, int nbatch) {
#pragma clang fp contract(off)
  const int batch = blockIdx.x * 256 + threadIdx.x;
  if (batch >= nbatch) return;
  const int ib = blockIdx.y, inp = blockIdx.z;
  const float* __restrict__ src =
      (inp == 0 ? A : Bm) + (size_t)batch * 1024 + ib * 256;

  float hi[16], lo[16];
#pragma unroll
  for (int j = 0; j < 16; ++j) { hi[j] = 0.f; lo[j] = 0.f; }

  float4 cur[8], nxt[8];
#pragma unroll
  for (int q = 0; q < 8; ++q) cur[q] = *(const float4*)(src + q * 4);

#pragma unroll
  for (int r = 0; r < 8; ++r) {       // iteration r covers hi buckets 2r, 2r+1
    if (r < 7) {
#pragma unroll
      for (int q = 0; q < 8; ++q)
        nxt[q] = *(const float4*)(src + (r + 1) * 32 + q * 4);
    }
    // hi[2r]: elements 32r..32r+15, strict ascending (same order as before)
    {
      float a = 0.f;
      a += cur[0].x; a += cur[0].y; a += cur[0].z; a += cur[0].w;
      a += cur[1].x; a += cur[1].y; a += cur[1].z; a += cur[1].w;
      a += cur[2].x; a += cur[2].y; a += cur[2].z; a += cur[2].w;
      a += cur[3].x; a += cur[3].y; a += cur[3].z; a += cur[3].w;
      hi[2 * r] = a;
    }
    // hi[2r+1]: elements 32r+16..32r+31, strict ascending
    {
      float a = 0.f;
      a += cur[4].x; a += cur[4].y; a += cur[4].z; a += cur[4].w;
      a += cur[5].x; a += cur[5].y; a += cur[5].z; a += cur[5].w;
      a += cur[6].x; a += cur[6].y; a += cur[6].z; a += cur[6].w;
      a += cur[7].x; a += cur[7].y; a += cur[7].z; a += cur[7].w;
      hi[2 * r + 1] = a;
    }
    // lo updates, m = 2r then m = 2r+1 (ascending m, same order as before)
    lo[0]  += cur[0].x; lo[1]  += cur[0].y; lo[2]  += cur[0].z; lo[3]  += cur[0].w;
    lo[4]  += cur[1].x; lo[5]  += cur[1].y; lo[6]  += cur[1].z; lo[7]  += cur[1].w;
    lo[8]  += cur[2].x; lo[9]  += cur[2].y; lo[10] += cur[2].z; lo[11] += cur[2].w;
    lo[12] += cur[3].x; lo[13] += cur[3].y; lo[14] += cur[3].z; lo[15] += cur[3].w;
    lo[0]  += cur[4].x; lo[1]  += cur[4].y; lo[2]  += cur[4].z; lo[3]  += cur[4].w;
    lo[4]  += cur[5].x; lo[5]  += cur[5].y; lo[6]  += cur[5].z; lo[7]  += cur[5].w;
    lo[8]  += cur[6].x; lo[9]  += cur[6].y; lo[10] += cur[6].z; lo[11] += cur[6].w;
    lo[12] += cur[7].x; lo[13] += cur[7].y; lo[14] += cur[7].z; lo[15] += cur[7].w;
#pragma unroll
    for (int q = 0; q < 8; ++q) cur[q] = nxt[q];
  }

  const size_t r0 = (size_t)((ib * 2 + inp) * 32);
  float p[16];
  softmax16_np(hi, p);
#pragma unroll
  for (int j = 0; j < 16; ++j) ws1[(r0 + j) * nbatch + batch] = p[j];
  softmax16_np(lo, p);
#pragma unroll
  for (int j = 0; j < 16; ++j) ws1[(r0 + 16 + j) * nbatch + batch] = p[j];
}

// ---------------- K2: serial carry chain -> ws2 ----------------
__device__ __forceinline__ void k2_load(const float* __restrict__ ws1, int i,
                                        size_t batch, int nbatch, float* b) {
#pragma unroll
  for (int t = 0; t < 64; ++t)
    b[t] = ws1[(size_t)(i * 64 + t) * nbatch + batch];
}

__device__ __forceinline__ void k2_step(const float* b, float& cr0, float& cr1,
                                        float* __restrict__ ws2, int i,
                                        size_t batch, int nbatch) {
  float sl[16], sh[16], d0, d1;
  nibble_add_raw(b + 16, b + 48, cr0, cr1, sl, d0, d1);   // low add, carry in
  nibble_add_raw(b + 0,  b + 32, d0, d1, sh, cr0, cr1);   // high add, carry out
#pragma unroll
  for (int l = 0; l < 16; ++l) {
    ws2[(size_t)(i * 32 + l) * nbatch + batch] = sh[l];        // nib 0 = hi
    ws2[(size_t)(i * 32 + 16 + l) * nbatch + batch] = sl[l];   // nib 1 = lo
  }
}

extern "C" __global__ void __launch_bounds__(64, 1)
k2_chain(const float* __restrict__ ws1, float* __restrict__ ws2, int nbatch) {
  const size_t batch = (size_t)blockIdx.x * 64 + threadIdx.x;
  if (batch >= (size_t)nbatch) return;
  // reference quirk: initial carry [1.0] broadcasts to BOTH carry slots
  float cr0 = 1.0f, cr1 = 1.0f;
  float bufA[64], bufB[64];                 // static indexing only
  k2_load(ws1, 0, batch, nbatch, bufA);
  k2_load(ws1, 1, batch, nbatch, bufB);     // prefetch hides under einsum
  k2_step(bufA, cr0, cr1, ws2, 0, batch, nbatch);
  k2_load(ws1, 2, batch, nbatch, bufA);
  k2_step(bufB, cr0, cr1, ws2, 1, batch, nbatch);
  k2_load(ws1, 3, batch, nbatch, bufB);
  k2_step(bufA, cr0, cr1, ws2, 2, batch, nbatch);
  k2_step(bufB, cr0, cr1, ws2, 3, batch, nbatch);
}

// ------- K3: double output softmax + outer product -> O -------
// grid (nbatch/64, 2), block 256: 64 batches x 2 ib x 2 nib = 256 tasks.
extern "C" __global__ void __launch_bounds__(256, 4)
k3_out(const float* __restrict__ ws2, float* __restrict__ O, int nbatch) {
  __shared__ float pout[2][64][36];  // [ib_local][batch][hi 0..15 | lo 20..35]
  const int tid = threadIdx.x;
  const int batch0 = blockIdx.x * 64;
  const int ib0 = blockIdx.y * 2;
  if (batch0 >= nbatch) return;

  {
    const int ibl = tid >> 7;          // wave-uniform
    const int nib = (tid >> 6) & 1;    // wave-uniform
    const int bb = tid & 63;
    float x[16], p[16], p2[16];
#pragma unroll
    for (int l = 0; l < 16; ++l)
      x[l] = ws2[(size_t)((ib0 + ibl) * 32 + nib * 16 + l) * nbatch + batch0 + bb];
    softmax16_np(x, p);    // ps (nibble_add's output softmax)
    softmax16_np(p, p2);   // from_nibbles softmax (separable factor)
#pragma unroll
    for (int j = 0; j < 16; ++j) pout[ibl][bb][nib * 20 + j] = p2[j];
  }
  __syncthreads();

#pragma unroll
  for (int ibl = 0; ibl < 2; ++ibl) {
#pragma unroll
    for (int kk = 0; kk < 16; ++kk) {
      int flat = kk * 1024 + tid * 4;   // 64 batches x 256 bytes
      int bb = flat >> 8;
      int b0 = flat & 255;              // multiple of 4
      float ph = pout[ibl][bb][b0 >> 4];
      int lo = 20 + (b0 & 15);
      float4 o;
      o.x = ph * pout[ibl][bb][lo + 0];
      o.y = ph * pout[ibl][bb][lo + 1];
      o.z = ph * pout[ibl][bb][lo + 2];
      o.w = ph * pout[ibl][bb][lo + 3];
      *(float4*)(O + ((size_t)(batch0 + bb) * 4 + ib0 + ibl) * 256 + b0) = o;
    }
  }
}

// ---------------- Fallback: known-passing single kernel (R4) ----------------
__device__ __forceinline__ void nibble_add_np_fb(const float* px, const float* py,
                                                 float c0, float c1,
                                                 float* ps, float& n0, float& n1) {
  float s[16];
  nibble_add_raw(px, py, c0, c1, s, n0, n1);
  softmax16_np(s, ps);
}

__device__ __forceinline__ void buckets_np_fb(const float* __restrict__ row,
                                              float* hi, float* lo) {
#pragma clang fp contract(off)
#pragma unroll
  for (int j = 0; j < 16; ++j) { hi[j] = 0.f; lo[j] = 0.f; }
#pragma unroll
  for (int k4 = 0; k4 < 64; ++k4) {
    float4 x = *(const float4*)(row + k4 * 4);
    const int h = k4 >> 2, l0 = (k4 & 3) * 4;
    hi[h] += x.x;  hi[h] += x.y;  hi[h] += x.z;  hi[h] += x.w;
    lo[l0 + 0] += x.x;
    lo[l0 + 1] += x.y;
    lo[l0 + 2] += x.z;
    lo[l0 + 3] += x.w;
  }
}

extern "C" __global__ void __launch_bounds__(64, 1)
byteadd_fallback(const float* __restrict__ A, const float* __restrict__ Bm,
                 float* __restrict__ O, int nbatch) {
#pragma clang fp contract(off)
  const int b = blockIdx.x * 64 + threadIdx.x;
  if (b >= nbatch) return;
  const float* Ab = A + (size_t)b * 1024;
  const float* Bb = Bm + (size_t)b * 1024;
  float* Ob = O + (size_t)b * 1024;
  float cr0 = 1.0f, cr1 = 1.0f;
#pragma unroll 1
  for (int i = 0; i < 4; ++i) {
    float ah[16], al[16], bh[16], bl[16];
    buckets_np_fb(Ab + i * 256, ah, al);
    buckets_np_fb(Bb + i * 256, bh, bl);
    float pah[16], pal[16], pbh[16], pbl[16];
    softmax16_np(ah, pah);
    softmax16_np(al, pal);
    softmax16_np(bh, pbh);
    softmax16_np(bl, pbl);
    float psl[16], psh[16], d0, d1;
    nibble_add_np_fb(pal, pbl, cr0, cr1, psl, d0, d1);
    nibble_add_np_fb(pah, pbh, d0, d1, psh, cr0, cr1);
    float ph2[16], pl2[16];
    softmax16_np(psh, ph2);
    softmax16_np(psl, pl2);
#pragma unroll
    for (int k4 = 0; k4 < 64; ++k4) {
      const int h = k4 >> 2, l0 = (k4 & 3) * 4;
      const float ph = ph2[h];
      float4 o;
      o.x = ph * pl2[l0 + 0];
      o.y = ph * pl2[l0 + 1];
      o.z = ph * pl2[l0 + 2];
      o.w = ph * pl2[l0 + 3];
      *(float4*)(Ob + i * 256 + k4 * 4) = o;
    }
  }
}

extern "C" void kernel_launch(void* const* d_in, const int* in_sizes, int n_in,
                              void* d_out, int out_size, void* d_ws, size_t ws_size,
                              hipStream_t stream) {
  const float* A = (const float*)d_in[0];
  const float* B = (const float*)d_in[1];
  float* O = (float*)d_out;
  int nbatch = in_sizes[0] / 1024;                       // [B,4,256] -> B
  size_t need = (size_t)384 * nbatch * sizeof(float);    // ws1(256*B) + ws2(128*B)
  if (ws_size >= need && (nbatch & 255) == 0) {
    float* ws1 = (float*)d_ws;
    float* ws2 = ws1 + (size_t)256 * nbatch;
    k1_prep<<<dim3(nbatch / 256, 4, 2), dim3(256), 0, stream>>>(A, B, ws1, nbatch);
    k2_chain<<<dim3(nbatch / 64), dim3(64), 0, stream>>>(ws1, ws2, nbatch);
    k3_out<<<dim3(nbatch / 64, 2), dim3(256), 0, stream>>>(ws2, O, nbatch);
  } else {
    byteadd_fallback<<<dim3((nbatch + 63) / 64), dim3(64), 0, stream>>>(A, B, O, nbatch);
  }
}

// Round 10
// 196.628 us; speedup vs baseline: 1.4284x; 1.4284x over previous
//
#include <hip/hip_runtime.h>
#include <cstddef>
#include <math.h>

// 3-kernel pipeline, numerics FROZEN to the passing R4..R9 recipe
// (absmax 0.015625 vs threshold 0.02): numpy-f32 op ordering everywhere —
// ascending per-bucket sums, scale-first softmax with pairwise-16 sum and
// true division, (i,j,k)-lex einsum with materialized-w rounding, f64-exact
// exp. R10 change vs R9: K1 REBUILT with coalesced LDS staging.
//   Per-thread-row K1 was cornered: needs 8xfloat4 live buffer (88 VGPR ->
//   2 blocks/CU, latency-bound, 155us) OR 64-VGPR cap (loads re-serialized
//   -> every 128B line fetched twice, 532MB, 190us). Now: waves stage whole
//   1KB rows (perfectly coalesced), bucket sums read LDS scalars with row
//   stride 261 (mod 32 = 5, coprime -> 2-way alias = free), softmax on a
//   fully-active wave. 37.6KB LDS -> 4 blocks/CU. Per-bucket FP add order
//   is bit-identical to R4..R9.

__device__ __forceinline__ float exf(float t) {
  return (float)exp((double)t);  // correctly-rounded f32 exp
}

// softmax(x*100) with numpy rounding/order.
__device__ __forceinline__ void softmax16_np(const float* x, float* p) {
#pragma clang fp contract(off)
  float t[16];
#pragma unroll
  for (int j = 0; j < 16; ++j) t[j] = x[j] * 100.0f;  // scale FIRST (rounded)
  float m = t[0];
#pragma unroll
  for (int j = 1; j < 16; ++j) m = fmaxf(m, t[j]);
  float e[16];
#pragma unroll
  for (int j = 0; j < 16; ++j) e[j] = exf(t[j] - m);
  float r0 = e[0] + e[8], r1 = e[1] + e[9], r2 = e[2] + e[10], r3 = e[3] + e[11];
  float r4 = e[4] + e[12], r5 = e[5] + e[13], r6 = e[6] + e[14], r7 = e[7] + e[15];
  float s = ((r0 + r1) + (r2 + r3)) + ((r4 + r5) + (r6 + r7));
#pragma unroll
  for (int j = 0; j < 16; ++j) p[j] = e[j] / s;  // true division
}

// Serial soft nibble add: raw sums s[16] (pre-softmax) + carry probs (n0,n1).
__device__ __forceinline__ void nibble_add_raw(const float* px, const float* py,
                                               float c0, float c1,
                                               float* s, float& n0, float& n1) {
#pragma clang fp contract(off)
  float ca = 0.f, cb = 0.f;
#pragma unroll
  for (int l = 0; l < 16; ++l) s[l] = 0.f;
#pragma unroll
  for (int i = 0; i < 16; ++i) {
#pragma unroll
    for (int j = 0; j < 16; ++j) {
      float wij = px[i] * py[j];
      float w0 = wij * c0;
      float w1 = wij * c1;
      const int t0 = i + j, t1 = i + j + 1;
      s[t0 & 15] += w0;
      if (t0 < 16) ca += w0; else cb += w0;
      s[t1 & 15] += w1;
      if (t1 < 16) ca += w1; else cb += w1;
    }
  }
  float u0 = ca * 100.0f, u1 = cb * 100.0f;
  float m = fmaxf(u0, u1);
  float e0 = exf(u0 - m), e1 = exf(u1 - m);
  float ss = e0 + e1;
  n0 = e0 / ss;
  n1 = e1 / ss;
}

// ---------------- K1: buckets + input softmax -> ws1 ----------------
// ws1 row r = (ib*2+inp)*32 + nib*16 + j  (256 rows x nbatch, batch-major)
// grid (nbatch/32, 4, 2), block 256 = 4 waves. 32 batches per block.
extern "C" __global__ void __launch_bounds__(256, 4)
k1_prep(const float* __restrict__ A, const float* __restrict__ Bm,
        float* __restrict__ ws1, int nbatch) {
#pragma clang fp contract(off)
  __shared__ float buf[32][261];   // stride 261: mod 32 = 5 (coprime) -> free
  __shared__ float comb[32][33];   // hi 0..15 | lo 16..31
  const int tid = threadIdx.x;
  const int wave = tid >> 6, lane = tid & 63;
  const int batch0 = blockIdx.x * 32;
  const int ib = blockIdx.y, inp = blockIdx.z;
  if (batch0 >= nbatch) return;
  const float* __restrict__ src =
      (inp == 0 ? A : Bm) + (size_t)batch0 * 1024 + ib * 256;

  // ---- stage: each wave loads whole 1KB rows, fully coalesced ----
#pragma unroll
  for (int it = 0; it < 8; ++it) {
    const int bb = it * 4 + wave;
    *(float4*)&buf[bb][lane * 4] =
        *(const float4*)(src + (size_t)bb * 1024 + lane * 4);
  }
  __syncthreads();

  // ---- bucket sums: 8 threads/batch, scalar reads, exact ascending order ----
  {
    const int g = tid >> 5;        // 0..7 (two g per wave -> uniform branches)
    const int bb = tid & 31;
    if (g < 4) {
      // hi buckets u = 4g+q: elements 16u..16u+15, ascending
#pragma unroll
      for (int q = 0; q < 4; ++q) {
        const int u = g * 4 + q;
        float a = 0.f;
#pragma unroll
        for (int e = 0; e < 16; ++e) a += buf[bb][u * 16 + e];
        comb[bb][u] = a;
      }
    } else {
      // lo buckets l = 4(g-4)+q: elements l+16m, m ascending
#pragma unroll
      for (int q = 0; q < 4; ++q) {
        const int l = (g - 4) * 4 + q;
        float a = 0.f;
#pragma unroll
        for (int m = 0; m < 16; ++m) a += buf[bb][m * 16 + l];
        comb[bb][16 + l] = a;
      }
    }
  }
  __syncthreads();

  // ---- input softmaxes: 64 tasks on a fully-active wave ----
  if (tid < 64) {
    const int bb = tid & 31, nib = tid >> 5;
    float x[16], p[16];
#pragma unroll
    for (int j = 0; j < 16; ++j) x[j] = comb[bb][nib * 16 + j];
    softmax16_np(x, p);
    const size_t r0 = (size_t)((ib * 2 + inp) * 32 + nib * 16);
#pragma unroll
    for (int j = 0; j < 16; ++j)
      ws1[(r0 + j) * nbatch + batch0 + bb] = p[j];
  }
}

// ---------------- K2: serial carry chain -> ws2 ----------------
__device__ __forceinline__ void k2_load(const float* __restrict__ ws1, int i,
                                        size_t batch, int nbatch, float* b) {
#pragma unroll
  for (int t = 0; t < 64; ++t)
    b[t] = ws1[(size_t)(i * 64 + t) * nbatch + batch];
}

__device__ __forceinline__ void k2_step(const float* b, float& cr0, float& cr1,
                                        float* __restrict__ ws2, int i,
                                        size_t batch, int nbatch) {
  float sl[16], sh[16], d0, d1;
  nibble_add_raw(b + 16, b + 48, cr0, cr1, sl, d0, d1);   // low add, carry in
  nibble_add_raw(b + 0,  b + 32, d0, d1, sh, cr0, cr1);   // high add, carry out
#pragma unroll
  for (int l = 0; l < 16; ++l) {
    ws2[(size_t)(i * 32 + l) * nbatch + batch] = sh[l];        // nib 0 = hi
    ws2[(size_t)(i * 32 + 16 + l) * nbatch + batch] = sl[l];   // nib 1 = lo
  }
}

extern "C" __global__ void __launch_bounds__(64, 1)
k2_chain(const float* __restrict__ ws1, float* __restrict__ ws2, int nbatch) {
  const size_t batch = (size_t)blockIdx.x * 64 + threadIdx.x;
  if (batch >= (size_t)nbatch) return;
  // reference quirk: initial carry [1.0] broadcasts to BOTH carry slots
  float cr0 = 1.0f, cr1 = 1.0f;
  float bufA[64], bufB[64];                 // static indexing only
  k2_load(ws1, 0, batch, nbatch, bufA);
  k2_load(ws1, 1, batch, nbatch, bufB);     // prefetch hides under einsum
  k2_step(bufA, cr0, cr1, ws2, 0, batch, nbatch);
  k2_load(ws1, 2, batch, nbatch, bufA);
  k2_step(bufB, cr0, cr1, ws2, 1, batch, nbatch);
  k2_load(ws1, 3, batch, nbatch, bufB);
  k2_step(bufA, cr0, cr1, ws2, 2, batch, nbatch);
  k2_step(bufB, cr0, cr1, ws2, 3, batch, nbatch);
}

// ------- K3: double output softmax + outer product -> O -------
// grid (nbatch/64, 2), block 256: 64 batches x 2 ib x 2 nib = 256 tasks.
extern "C" __global__ void __launch_bounds__(256, 4)
k3_out(const float* __restrict__ ws2, float* __restrict__ O, int nbatch) {
  __shared__ float pout[2][64][36];  // [ib_local][batch][hi 0..15 | lo 20..35]
  const int tid = threadIdx.x;
  const int batch0 = blockIdx.x * 64;
  const int ib0 = blockIdx.y * 2;
  if (batch0 >= nbatch) return;

  {
    const int ibl = tid >> 7;          // wave-uniform
    const int nib = (tid >> 6) & 1;    // wave-uniform
    const int bb = tid & 63;
    float x[16], p[16], p2[16];
#pragma unroll
    for (int l = 0; l < 16; ++l)
      x[l] = ws2[(size_t)((ib0 + ibl) * 32 + nib * 16 + l) * nbatch + batch0 + bb];
    softmax16_np(x, p);    // ps (nibble_add's output softmax)
    softmax16_np(p, p2);   // from_nibbles softmax (separable factor)
#pragma unroll
    for (int j = 0; j < 16; ++j) pout[ibl][bb][nib * 20 + j] = p2[j];
  }
  __syncthreads();

#pragma unroll
  for (int ibl = 0; ibl < 2; ++ibl) {
#pragma unroll
    for (int kk = 0; kk < 16; ++kk) {
      int flat = kk * 1024 + tid * 4;   // 64 batches x 256 bytes
      int bb = flat >> 8;
      int b0 = flat & 255;              // multiple of 4
      float ph = pout[ibl][bb][b0 >> 4];
      int lo = 20 + (b0 & 15);
      float4 o;
      o.x = ph * pout[ibl][bb][lo + 0];
      o.y = ph * pout[ibl][bb][lo + 1];
      o.z = ph * pout[ibl][bb][lo + 2];
      o.w = ph * pout[ibl][bb][lo + 3];
      *(float4*)(O + ((size_t)(batch0 + bb) * 4 + ib0 + ibl) * 256 + b0) = o;
    }
  }
}

// ---------------- Fallback: known-passing single kernel (R4) ----------------
__device__ __forceinline__ void nibble_add_np_fb(const float* px, const float* py,
                                                 float c0, float c1,
                                                 float* ps, float& n0, float& n1) {
  float s[16];
  nibble_add_raw(px, py, c0, c1, s, n0, n1);
  softmax16_np(s, ps);
}

__device__ __forceinline__ void buckets_np_fb(const float* __restrict__ row,
                                              float* hi, float* lo) {
#pragma clang fp contract(off)
#pragma unroll
  for (int j = 0; j < 16; ++j) { hi[j] = 0.f; lo[j] = 0.f; }
#pragma unroll
  for (int k4 = 0; k4 < 64; ++k4) {
    float4 x = *(const float4*)(row + k4 * 4);
    const int h = k4 >> 2, l0 = (k4 & 3) * 4;
    hi[h] += x.x;  hi[h] += x.y;  hi[h] += x.z;  hi[h] += x.w;
    lo[l0 + 0] += x.x;
    lo[l0 + 1] += x.y;
    lo[l0 + 2] += x.z;
    lo[l0 + 3] += x.w;
  }
}

extern "C" __global__ void __launch_bounds__(64, 1)
byteadd_fallback(const float* __restrict__ A, const float* __restrict__ Bm,
                 float* __restrict__ O, int nbatch) {
#pragma clang fp contract(off)
  const int b = blockIdx.x * 64 + threadIdx.x;
  if (b >= nbatch) return;
  const float* Ab = A + (size_t)b * 1024;
  const float* Bb = Bm + (size_t)b * 1024;
  float* Ob = O + (size_t)b * 1024;
  float cr0 = 1.0f, cr1 = 1.0f;
#pragma unroll 1
  for (int i = 0; i < 4; ++i) {
    float ah[16], al[16], bh[16], bl[16];
    buckets_np_fb(Ab + i * 256, ah, al);
    buckets_np_fb(Bb + i * 256, bh, bl);
    float pah[16], pal[16], pbh[16], pbl[16];
    softmax16_np(ah, pah);
    softmax16_np(al, pal);
    softmax16_np(bh, pbh);
    softmax16_np(bl, pbl);
    float psl[16], psh[16], d0, d1;
    nibble_add_np_fb(pal, pbl, cr0, cr1, psl, d0, d1);
    nibble_add_np_fb(pah, pbh, d0, d1, psh, cr0, cr1);
    float ph2[16], pl2[16];
    softmax16_np(psh, ph2);
    softmax16_np(psl, pl2);
#pragma unroll
    for (int k4 = 0; k4 < 64; ++k4) {
      const int h = k4 >> 2, l0 = (k4 & 3) * 4;
      const float ph = ph2[h];
      float4 o;
      o.x = ph * pl2[l0 + 0];
      o.y = ph * pl2[l0 + 1];
      o.z = ph * pl2[l0 + 2];
      o.w = ph * pl2[l0 + 3];
      *(float4*)(Ob + i * 256 + k4 * 4) = o;
    }
  }
}

extern "C" void kernel_launch(void* const* d_in, const int* in_sizes, int n_in,
                              void* d_out, int out_size, void* d_ws, size_t ws_size,
                              hipStream_t stream) {
  const float* A = (const float*)d_in[0];
  const float* B = (const float*)d_in[1];
  float* O = (float*)d_out;
  int nbatch = in_sizes[0] / 1024;                       // [B,4,256] -> B
  size_t need = (size_t)384 * nbatch * sizeof(float);    // ws1(256*B) + ws2(128*B)
  if (ws_size >= need && (nbatch & 63) == 0) {
    float* ws1 = (float*)d_ws;
    float* ws2 = ws1 + (size_t)256 * nbatch;
    k1_prep<<<dim3(nbatch / 32, 4, 2), dim3(256), 0, stream>>>(A, B, ws1, nbatch);
    k2_chain<<<dim3(nbatch / 64), dim3(64), 0, stream>>>(ws1, ws2, nbatch);
    k3_out<<<dim3(nbatch / 64, 2), dim3(256), 0, stream>>>(ws2, O, nbatch);
  } else {
    byteadd_fallback<<<dim3((nbatch + 63) / 64), dim3(64), 0, stream>>>(A, B, O, nbatch);
  }
}